// Round 1
// baseline (425.559 us; speedup 1.0000x reference)
//
#include <hip/hip_runtime.h>
#include <math.h>

// ProbLoss: B=16, T=2048, D=512, C=20. Inputs (f32):
//   d_in[0] attn [B,T,1], d_in[1] mu [B,T,D], d_in[2] var [B,T,D],
//   d_in[3] mu_clip [B,T,D], d_in[4] text_feat [C,D], d_in[5] drop_mask [B,T]
// Output: 5 f32 scalars (total, distill, act_loss, bkg_loss, ortho).

#define BB 16
#define TT 2048
#define DD 512
#define CC 20
#define KEASY 40
#define KHARD 20
#define EPSF 1e-5f

// ---------------- helpers ----------------
__device__ __forceinline__ float wred(float v) {
#pragma unroll
  for (int off = 32; off; off >>= 1) v += __shfl_xor(v, off, 64);
  return v;
}

// ---------------- init: zero f64 accumulators ----------------
__global__ void k_init(double* acc) {
  int i = threadIdx.x;
  if (i < 66) acc[i] = 0.0;
}

// ---------------- per-batch median (exact, even-T mean of middles) + max ----
__global__ __launch_bounds__(256) void k_medmax(const float* __restrict__ attn,
                                                float* __restrict__ medmax) {
  __shared__ float s[TT];
  const int b = blockIdx.x, tid = threadIdx.x;
  for (int i = tid; i < TT; i += 256) s[i] = attn[b * TT + i];
  __syncthreads();
  // bitonic ascending sort of 2048 f32 (all in [0,1), no NaN)
  for (int kk = 2; kk <= TT; kk <<= 1) {
    for (int jj = kk >> 1; jj > 0; jj >>= 1) {
      for (int i = tid; i < TT; i += 256) {
        int ixj = i ^ jj;
        if (ixj > i) {
          float x = s[i], y = s[ixj];
          bool up = ((i & kk) == 0);
          if (up ? (x > y) : (x < y)) { s[i] = y; s[ixj] = x; }
        }
      }
      __syncthreads();
    }
  }
  if (tid == 0) {
    medmax[b] = 0.5f * (s[TT / 2 - 1] + s[TT / 2]);  // np/jnp median, even count
    medmax[16 + b] = s[TT - 1];                      // max
  }
}

// ---------------- per-(batch,selection) exact top-k via u64 bitonic sort ----
// sel 0: a*drop (k=40)   sel 1: (max-a)*drop (k=40)
// sel 2: a*inner (k=20)  sel 3: a*outer (k=20)
// key = (score_bits<<32) | (2047 - t): descending sort == JAX stable top_k.
__global__ __launch_bounds__(256) void k_topk(const float* __restrict__ attn,
                                              const float* __restrict__ drop,
                                              const float* __restrict__ medmax,
                                              int* __restrict__ idxb) {
  __shared__ float s_a[TT];
  __shared__ float s_w[TT];  // drop (sel<2) or binary mask (sel>=2)
  __shared__ unsigned long long s_key[TT];
  const int b = blockIdx.x >> 2, sel = blockIdx.x & 3;
  const int tid = threadIdx.x;
  const float med = medmax[b], mx = medmax[16 + b];
  for (int i = tid; i < TT; i += 256) {
    float a = attn[b * TT + i];
    s_a[i] = a;
    s_w[i] = (sel < 2) ? drop[b * TT + i] : ((a > med) ? 1.0f : 0.0f);
  }
  __syncthreads();
  for (int i = tid; i < TT; i += 256) {
    float a = s_a[i];
    float score;
    if (sel == 0) {
      score = a * s_w[i];
    } else if (sel == 1) {
      score = (mx - a) * s_w[i];
    } else {
      bool small_all = true, big_all = true, small_any = false, big_any = false;
#pragma unroll
      for (int o = -3; o <= 3; o++) {
        int t = i + o;
        bool one = (t >= 0 && t < TT) ? (s_w[t] > 0.5f) : false;  // zero pad
        if (o >= -1 && o <= 1) { small_all = small_all && one; small_any = small_any || one; }
        big_all = big_all && one;
        big_any = big_any || one;
      }
      if (sel == 2) {  // inner = erosion3 && !erosion7
        score = (small_all && !big_all) ? a : 0.0f;
      } else {         // outer = dilation7 && !dilation3
        score = (big_any && !small_any) ? a : 0.0f;
      }
    }
    // scores are all >= +0, so bits compare monotonically
    s_key[i] = ((unsigned long long)__float_as_uint(score) << 32) |
               (unsigned long long)(unsigned)(TT - 1 - i);
  }
  __syncthreads();
  for (int kk = 2; kk <= TT; kk <<= 1) {
    for (int jj = kk >> 1; jj > 0; jj >>= 1) {
      for (int i = tid; i < TT; i += 256) {
        int ixj = i ^ jj;
        if (ixj > i) {
          unsigned long long x = s_key[i], y = s_key[ixj];
          bool up = ((i & kk) == 0);
          if (up ? (x < y) : (x > y)) { s_key[i] = y; s_key[ixj] = x; }  // descending
        }
      }
      __syncthreads();
    }
  }
  const int kk2 = (sel < 2) ? KEASY : KHARD;
  if (tid < kk2) {
    int t = (TT - 1) - (int)(s_key[tid] & 0xffffffffULL);
    idxb[sel * (BB * KEASY) + b * KEASY + tid] = t;
  }
}

// ---------------- per selected row: sum_d log(var+eps) ----------------
__global__ __launch_bounds__(256) void k_slog(const float* __restrict__ var,
                                              const int* __restrict__ idxb,
                                              float* __restrict__ slogb) {
  const int g = blockIdx.x * 4 + (threadIdx.x >> 6);  // 1920 waves total
  const int lane = threadIdx.x & 63;
  int sel, b, j;
  if (g < 1280) { sel = g / 640; int r = g % 640; b = r / 40; j = r % 40; }
  else { int g2 = g - 1280; sel = 2 + g2 / 320; int r = g2 % 320; b = r / 20; j = r % 20; }
  const int t = idxb[sel * 640 + b * 40 + j];
  const float* row = var + ((size_t)b * TT + t) * DD;
  float acc = 0.f;
#pragma unroll
  for (int c = 0; c < 2; c++) {
    float4 v = *(const float4*)(row + c * 256 + lane * 4);
    acc += logf(v.x + EPSF) + logf(v.y + EPSF) + logf(v.z + EPSF) + logf(v.w + EPSF);
  }
  acc = wred(acc);
  if (lane == 0) slogb[sel * 640 + b * 40 + j] = acc;
}

// ---------------- KL: one block per (klid, b, ip); 40 q's over 4 waves -----
// klid0: p=hard_act(2), q=easy_act(0) -> pos_act
// klid1: p=hard_act(2), q=easy_bkg(1) -> neg_act
// klid2: p=hard_bkg(3), q=easy_bkg(1) -> pos_bkg
// klid3: p=hard_bkg(3), q=easy_act(0) -> neg_bkg
__global__ __launch_bounds__(256) void k_kl(const float* __restrict__ mu,
                                            const float* __restrict__ var,
                                            const int* __restrict__ idxb,
                                            const float* __restrict__ slogb,
                                            double* __restrict__ acc) {
  __shared__ __align__(16) float s_mup[DD];
  __shared__ __align__(16) float s_cvp[DD];
  __shared__ float s_red[4];
  const int blk = blockIdx.x;
  const int klid = blk / 320, rem = blk % 320, b = rem / 20, ip = rem % 20;
  const int psel = (klid < 2) ? 2 : 3;
  const int qsel = (klid == 0) ? 0 : (klid == 1) ? 1 : (klid == 2) ? 1 : 0;
  const int tid = threadIdx.x, wid = tid >> 6, lane = tid & 63;
  const int pidx = idxb[psel * 640 + b * 40 + ip];
  const float slog_p = slogb[psel * 640 + b * 40 + ip];
  const size_t pbase = ((size_t)b * TT + pidx) * DD;
  for (int i = tid; i < DD; i += 256) {
    s_mup[i] = mu[pbase + i];
    s_cvp[i] = var[pbase + i] + EPSF;
  }
  __syncthreads();
  float wacc = 0.f;
  for (int iq = wid; iq < KEASY; iq += 4) {
    const int qidx = idxb[qsel * 640 + b * 40 + iq];
    const float slog_q = slogb[qsel * 640 + b * 40 + iq];
    const size_t qbase = ((size_t)b * TT + qidx) * DD;
    float a1 = 0.f, a3 = 0.f;
#pragma unroll
    for (int c = 0; c < 2; c++) {
      const int d0 = c * 256 + lane * 4;
      float4 mq = *(const float4*)(mu + qbase + d0);
      float4 vq = *(const float4*)(var + qbase + d0);
      float4 mp = *(const float4*)(&s_mup[d0]);
      float4 cp = *(const float4*)(&s_cvp[d0]);
      { float r = 1.0f / (vq.x + EPSF); float df = mq.x - mp.x; a1 += df * df * r; a3 += cp.x * r; }
      { float r = 1.0f / (vq.y + EPSF); float df = mq.y - mp.y; a1 += df * df * r; a3 += cp.y * r; }
      { float r = 1.0f / (vq.z + EPSF); float df = mq.z - mp.z; a1 += df * df * r; a3 += cp.z * r; }
      { float r = 1.0f / (vq.w + EPSF); float df = mq.w - mp.w; a1 += df * df * r; a3 += cp.w * r; }
    }
    a1 = wred(a1);
    a3 = wred(a3);
    if (lane == 0) {
      float dist = 0.5f * a1 + 0.5f * (slog_q - slog_p) + 0.5f * a3 - 0.5f * (float)DD;
      wacc += 1.0f / (dist + 1.0f);
    }
  }
  if (lane == 0) s_red[wid] = wacc;
  __syncthreads();
  if (tid == 0) {
    double sum = (double)s_red[0] + s_red[1] + s_red[2] + s_red[3];
    atomicAdd(&acc[1 + klid * 16 + b], sum);
  }
}

// ---------------- distill: sum over B*T of (cos(mu,mu_clip)+1)/2 ----------
__global__ __launch_bounds__(256) void k_distill(const float* __restrict__ mu,
                                                 const float* __restrict__ muc,
                                                 float* __restrict__ part) {
  __shared__ float s_red[4];
  const int tid = threadIdx.x, wid = tid >> 6, lane = tid & 63;
  float wsum = 0.f;
#pragma unroll
  for (int it = 0; it < 4; it++) {
    const int r = blockIdx.x * 4 + wid + it * 8192;  // covers 0..32767
    const size_t base = (size_t)r * DD;
    float dot = 0.f, n1 = 0.f, n2 = 0.f;
#pragma unroll
    for (int c = 0; c < 2; c++) {
      const int d0 = c * 256 + lane * 4;
      float4 x = *(const float4*)(mu + base + d0);
      float4 y = *(const float4*)(muc + base + d0);
      dot = fmaf(x.x, y.x, fmaf(x.y, y.y, fmaf(x.z, y.z, fmaf(x.w, y.w, dot))));
      n1 = fmaf(x.x, x.x, fmaf(x.y, x.y, fmaf(x.z, x.z, fmaf(x.w, x.w, n1))));
      n2 = fmaf(y.x, y.x, fmaf(y.y, y.y, fmaf(y.z, y.z, fmaf(y.w, y.w, n2))));
    }
#pragma unroll
    for (int off = 32; off; off >>= 1) {
      dot += __shfl_xor(dot, off, 64);
      n1 += __shfl_xor(n1, off, 64);
      n2 += __shfl_xor(n2, off, 64);
    }
    if (lane == 0) {
      float sim = dot / (fmaxf(sqrtf(n1), 1e-12f) * fmaxf(sqrtf(n2), 1e-12f));
      wsum += (sim + 1.0f) * 0.5f;
    }
  }
  if (lane == 0) s_red[wid] = wsum;
  __syncthreads();
  if (tid == 0) part[blockIdx.x] = s_red[0] + s_red[1] + s_red[2] + s_red[3];
}

// ---------------- ortho: ||normalize(text) @ normalize(text)^T - I||_F ----
__global__ __launch_bounds__(256) void k_ortho(const float* __restrict__ text,
                                               double* __restrict__ acc) {
  __shared__ __align__(16) float s_e[CC * DD];  // 40 KB
  __shared__ float s_red[4];
  const int tid = threadIdx.x, wid = tid >> 6, lane = tid & 63;
  for (int r = wid; r < CC; r += 4) {
    float4 v[2];
    float ss = 0.f;
#pragma unroll
    for (int c = 0; c < 2; c++) {
      v[c] = *(const float4*)(text + r * DD + c * 256 + lane * 4);
      ss += v[c].x * v[c].x + v[c].y * v[c].y + v[c].z * v[c].z + v[c].w * v[c].w;
    }
    ss = wred(ss);
    float n = fmaxf(sqrtf(ss), 1e-12f);
#pragma unroll
    for (int c = 0; c < 2; c++) {
      float4 w = v[c];
      w.x /= n; w.y /= n; w.z /= n; w.w /= n;
      *(float4*)(&s_e[r * DD + c * 256 + lane * 4]) = w;
    }
  }
  __syncthreads();
  float wss = 0.f;
  for (int p = wid; p < CC * CC; p += 4) {
    const int i = p / CC, j = p % CC;
    float dot = 0.f;
#pragma unroll
    for (int c = 0; c < 2; c++) {
      const int d0 = c * 256 + lane * 4;
      float4 x = *(const float4*)(&s_e[i * DD + d0]);
      float4 y = *(const float4*)(&s_e[j * DD + d0]);
      dot += x.x * y.x + x.y * y.y + x.z * y.z + x.w * y.w;
    }
    dot = wred(dot);
    if (lane == 0) {
      float s = dot - (i == j ? 1.0f : 0.0f);
      wss += s * s;
    }
  }
  if (lane == 0) s_red[wid] = wss;
  __syncthreads();
  if (tid == 0) acc[65] = (double)(s_red[0] + s_red[1] + s_red[2] + s_red[3]);
}

// ---------------- finalize ----------------
__global__ __launch_bounds__(256) void k_final(const double* __restrict__ acc,
                                               const float* __restrict__ part,
                                               float* __restrict__ out) {
  __shared__ double s_red[256];
  const int tid = threadIdx.x;
  double s = 0.0;
  for (int i = tid; i < 2048; i += 256) s += (double)part[i];
  s_red[tid] = s;
  __syncthreads();
  for (int st = 128; st; st >>= 1) {
    if (tid < st) s_red[tid] += s_red[tid + st];
    __syncthreads();
  }
  if (tid == 0) {
    double distill = -log(s_red[0] / (double)(BB * TT));
    double act = 0.0, bkg = 0.0;
    for (int b = 0; b < 16; b++) {
      double pa = acc[1 + 0 * 16 + b] / 800.0;
      double na = acc[1 + 1 * 16 + b] / 800.0;
      double pb = acc[1 + 2 * 16 + b] / 800.0;
      double nb = acc[1 + 3 * 16 + b] / 800.0;
      act += -(log(pa) + log(1.0 - na));
      bkg += -(log(pb) + log(1.0 - nb));
    }
    act /= 16.0;
    bkg /= 16.0;
    double ortho = sqrt(acc[65]);
    double total = distill + act + bkg + ortho;
    out[0] = (float)total;
    out[1] = (float)distill;
    out[2] = (float)act;
    out[3] = (float)bkg;
    out[4] = (float)ortho;
  }
}

extern "C" void kernel_launch(void* const* d_in, const int* in_sizes, int n_in,
                              void* d_out, int out_size, void* d_ws, size_t ws_size,
                              hipStream_t stream) {
  const float* attn = (const float*)d_in[0];
  const float* mu   = (const float*)d_in[1];
  const float* var  = (const float*)d_in[2];
  const float* muc  = (const float*)d_in[3];
  const float* text = (const float*)d_in[4];
  const float* drop = (const float*)d_in[5];
  float* out = (float*)d_out;

  // workspace layout (~30 KB)
  double* acc   = (double*)d_ws;            // 66 doubles: [1..64] kl sums, [65] ortho
  float* medmax = (float*)(acc + 66);       // 32 f32: med[16], max[16]
  int* idxb     = (int*)(medmax + 32);      // 4*16*40 ints
  float* slogb  = (float*)(idxb + 2560);    // 4*16*40 f32
  float* part   = (float*)(slogb + 2560);   // 2048 f32 distill partials

  k_init<<<1, 128, 0, stream>>>(acc);
  k_medmax<<<16, 256, 0, stream>>>(attn, medmax);
  k_topk<<<64, 256, 0, stream>>>(attn, drop, medmax, idxb);
  k_slog<<<480, 256, 0, stream>>>(var, idxb, slogb);
  k_kl<<<1280, 256, 0, stream>>>(mu, var, idxb, slogb, acc);
  k_distill<<<2048, 256, 0, stream>>>(mu, muc, part);
  k_ortho<<<1, 256, 0, stream>>>(text, acc);
  k_final<<<1, 256, 0, stream>>>(acc, part, out);
}

// Round 2
// 343.442 us; speedup vs baseline: 1.2391x; 1.2391x over previous
//
#include <hip/hip_runtime.h>
#include <math.h>

// ProbLoss: B=16, T=2048, D=512, C=20. Inputs (f32):
//   d_in[0] attn [B,T,1], d_in[1] mu [B,T,D], d_in[2] var [B,T,D],
//   d_in[3] mu_clip [B,T,D], d_in[4] text_feat [C,D], d_in[5] drop_mask [B,T]
// Output: 5 f32 scalars (total, distill, act_loss, bkg_loss, ortho).

#define BB 16
#define TT 2048
#define DD 512
#define CC 20
#define KEASY 40
#define KHARD 20
#define EPSF 1e-5f

typedef unsigned long long u64;

__device__ __forceinline__ float wred(float v) {
#pragma unroll
  for (int off = 32; off; off >>= 1) v += __shfl_xor(v, off, 64);
  return v;
}

// k-th largest key among the wave's 64x32 keys via binary search on the
// 43-bit key space. Keys are distinct (low 11 bits = 2047-index), so the
// result T satisfies |{key >= T}| == k exactly. No LDS, no barriers.
__device__ __forceinline__ u64 kth_key(const u64 (&keys)[32], unsigned k, u64 hi0) {
  u64 lo = 0, hi = hi0;
  while (lo < hi) {
    u64 mid = lo + ((hi - lo + 1) >> 1);
    unsigned c = 0;
#pragma unroll
    for (int r = 0; r < 32; r++) c += (keys[r] >= mid) ? 1u : 0u;
#pragma unroll
    for (int off = 32; off; off >>= 1) c += __shfl_xor(c, off, 64);
    if (c >= k) lo = mid; else hi = mid - 1;
  }
  return lo;
}

// ---------------- selection: one wave per (batch, sel) ----------------
// sel 0: top-40 of a*drop        sel 1: top-40 of (max-a)*drop
// sel 2: top-20 of a*inner       sel 3: top-20 of a*outer
// Output order within the k indices is arbitrary (downstream is a mean
// over all pairs). Set equality with JAX stable top_k is guaranteed by
// the distinct (score_bits<<11 | 2047-i) keys. Block 0 also zeroes acc.
__global__ __launch_bounds__(64) void k_select(const float* __restrict__ attn,
                                               const float* __restrict__ drop,
                                               int* __restrict__ idxb,
                                               double* __restrict__ acc) {
  __shared__ float s_a[TT];
  const int b = blockIdx.x >> 2, sel = blockIdx.x & 3;
  const int lane = threadIdx.x;
  if (blockIdx.x == 0) {  // zero the 66 f64 accumulators (ws is poisoned)
    acc[lane] = 0.0;
    if (lane < 2) acc[64 + lane] = 0.0;
  }
  float av[32], dv[32];
#pragma unroll
  for (int r = 0; r < 32; r++) {
    const int i = r * 64 + lane;
    float a = attn[b * TT + i];
    av[r] = a;
    s_a[i] = a;
    dv[r] = (sel < 2) ? drop[b * TT + i] : 0.f;
  }
  __syncthreads();

  const u64 HI0 = (((u64)0x7F800000u) << 11) | 0x7FFull;
  u64 keys[32];

  float mx = 0.f, med = 0.f;
  if (sel == 1) {
    float m = av[0];
#pragma unroll
    for (int r = 1; r < 32; r++) m = fmaxf(m, av[r]);
#pragma unroll
    for (int off = 32; off; off >>= 1) m = fmaxf(m, __shfl_xor(m, off, 64));
    mx = m;
  }
  if (sel >= 2) {
    // median = mean of 1024th and 1025th largest values (exact order stats)
#pragma unroll
    for (int r = 0; r < 32; r++)
      keys[r] = (((u64)__float_as_uint(av[r])) << 11) | (u64)(TT - 1 - (r * 64 + lane));
    u64 t1 = kth_key(keys, 1024, HI0);
    u64 t2 = kth_key(keys, 1025, t1);
    med = 0.5f * (__uint_as_float((unsigned)(t1 >> 11)) +
                  __uint_as_float((unsigned)(t2 >> 11)));
  }

#pragma unroll
  for (int r = 0; r < 32; r++) {
    const int i = r * 64 + lane;
    float score;
    if (sel == 0) {
      score = av[r] * dv[r];
    } else if (sel == 1) {
      score = (mx - av[r]) * dv[r];
    } else {
      bool sall = true, ball = true, sany = false, bany = false;
#pragma unroll
      for (int o = -3; o <= 3; o++) {
        int t = i + o;
        bool one = (t >= 0 && t < TT) ? (s_a[t] > med) : false;  // zero pad
        if (o >= -1 && o <= 1) { sall = sall && one; sany = sany || one; }
        ball = ball && one;
        bany = bany || one;
      }
      if (sel == 2) score = (sall && !ball) ? av[r] : 0.0f;  // er3 && !er7
      else          score = (bany && !sany) ? av[r] : 0.0f;  // dl7 && !dl3
    }
    // score >= +0 so float bits compare monotonically
    keys[r] = (((u64)__float_as_uint(score)) << 11) | (u64)(TT - 1 - i);
  }

  const unsigned K = (sel < 2) ? KEASY : KHARD;
  const u64 T = kth_key(keys, K, HI0);

  // compact-write the selected indices (arbitrary order)
  unsigned mine = 0;
#pragma unroll
  for (int r = 0; r < 32; r++) mine += (keys[r] >= T) ? 1u : 0u;
  unsigned scan = mine;
#pragma unroll
  for (int off = 1; off < 64; off <<= 1) {
    unsigned v = __shfl_up(scan, off, 64);
    if (lane >= off) scan += v;
  }
  unsigned pos = scan - mine;
  int* dst = idxb + sel * (BB * KEASY) + b * KEASY;
#pragma unroll
  for (int r = 0; r < 32; r++) {
    if (keys[r] >= T) dst[pos++] = r * 64 + lane;
  }
}

// ---------------- per selected row: sum_d log(var+eps) ----------------
__global__ __launch_bounds__(256) void k_slog(const float* __restrict__ var,
                                              const int* __restrict__ idxb,
                                              float* __restrict__ slogb) {
  const int g = blockIdx.x * 4 + (threadIdx.x >> 6);  // 1920 waves total
  const int lane = threadIdx.x & 63;
  int sel, b, j;
  if (g < 1280) { sel = g / 640; int r = g % 640; b = r / 40; j = r % 40; }
  else { int g2 = g - 1280; sel = 2 + g2 / 320; int r = g2 % 320; b = r / 20; j = r % 20; }
  const int t = idxb[sel * 640 + b * 40 + j];
  const float* row = var + ((size_t)b * TT + t) * DD;
  float acc = 0.f;
#pragma unroll
  for (int c = 0; c < 2; c++) {
    float4 v = *(const float4*)(row + c * 256 + lane * 4);
    acc += logf(v.x + EPSF) + logf(v.y + EPSF) + logf(v.z + EPSF) + logf(v.w + EPSF);
  }
  acc = wred(acc);
  if (lane == 0) slogb[sel * 640 + b * 40 + j] = acc;
}

// ---------------- KL: one block per (klid, b, ip); 40 q's over 4 waves -----
__global__ __launch_bounds__(256) void k_kl(const float* __restrict__ mu,
                                            const float* __restrict__ var,
                                            const int* __restrict__ idxb,
                                            const float* __restrict__ slogb,
                                            double* __restrict__ acc) {
  __shared__ __align__(16) float s_mup[DD];
  __shared__ __align__(16) float s_cvp[DD];
  __shared__ float s_red[4];
  const int blk = blockIdx.x;
  const int klid = blk / 320, rem = blk % 320, b = rem / 20, ip = rem % 20;
  const int psel = (klid < 2) ? 2 : 3;
  const int qsel = (klid == 0) ? 0 : (klid == 1) ? 1 : (klid == 2) ? 1 : 0;
  const int tid = threadIdx.x, wid = tid >> 6, lane = tid & 63;
  const int pidx = idxb[psel * 640 + b * 40 + ip];
  const float slog_p = slogb[psel * 640 + b * 40 + ip];
  const size_t pbase = ((size_t)b * TT + pidx) * DD;
  for (int i = tid; i < DD; i += 256) {
    s_mup[i] = mu[pbase + i];
    s_cvp[i] = var[pbase + i] + EPSF;
  }
  __syncthreads();
  float wacc = 0.f;
  for (int iq = wid; iq < KEASY; iq += 4) {
    const int qidx = idxb[qsel * 640 + b * 40 + iq];
    const float slog_q = slogb[qsel * 640 + b * 40 + iq];
    const size_t qbase = ((size_t)b * TT + qidx) * DD;
    float a1 = 0.f, a3 = 0.f;
#pragma unroll
    for (int c = 0; c < 2; c++) {
      const int d0 = c * 256 + lane * 4;
      float4 mq = *(const float4*)(mu + qbase + d0);
      float4 vq = *(const float4*)(var + qbase + d0);
      float4 mp = *(const float4*)(&s_mup[d0]);
      float4 cp = *(const float4*)(&s_cvp[d0]);
      { float r = 1.0f / (vq.x + EPSF); float df = mq.x - mp.x; a1 += df * df * r; a3 += cp.x * r; }
      { float r = 1.0f / (vq.y + EPSF); float df = mq.y - mp.y; a1 += df * df * r; a3 += cp.y * r; }
      { float r = 1.0f / (vq.z + EPSF); float df = mq.z - mp.z; a1 += df * df * r; a3 += cp.z * r; }
      { float r = 1.0f / (vq.w + EPSF); float df = mq.w - mp.w; a1 += df * df * r; a3 += cp.w * r; }
    }
    a1 = wred(a1);
    a3 = wred(a3);
    if (lane == 0) {
      float dist = 0.5f * a1 + 0.5f * (slog_q - slog_p) + 0.5f * a3 - 0.5f * (float)DD;
      wacc += 1.0f / (dist + 1.0f);
    }
  }
  if (lane == 0) s_red[wid] = wacc;
  __syncthreads();
  if (tid == 0) {
    double sum = (double)s_red[0] + s_red[1] + s_red[2] + s_red[3];
    atomicAdd(&acc[klid * 16 + b], sum);
  }
}

// ---------------- distill: sum over B*T of (cos(mu,mu_clip)+1)/2 ----------
__global__ __launch_bounds__(256) void k_distill(const float* __restrict__ mu,
                                                 const float* __restrict__ muc,
                                                 float* __restrict__ part) {
  __shared__ float s_red[4];
  const int tid = threadIdx.x, wid = tid >> 6, lane = tid & 63;
  float wsum = 0.f;
#pragma unroll
  for (int it = 0; it < 4; it++) {
    const int r = blockIdx.x * 4 + wid + it * 8192;  // covers 0..32767
    const size_t base = (size_t)r * DD;
    float dot = 0.f, n1 = 0.f, n2 = 0.f;
#pragma unroll
    for (int c = 0; c < 2; c++) {
      const int d0 = c * 256 + lane * 4;
      float4 x = *(const float4*)(mu + base + d0);
      float4 y = *(const float4*)(muc + base + d0);
      dot = fmaf(x.x, y.x, fmaf(x.y, y.y, fmaf(x.z, y.z, fmaf(x.w, y.w, dot))));
      n1 = fmaf(x.x, x.x, fmaf(x.y, x.y, fmaf(x.z, x.z, fmaf(x.w, x.w, n1))));
      n2 = fmaf(y.x, y.x, fmaf(y.y, y.y, fmaf(y.z, y.z, fmaf(y.w, y.w, n2))));
    }
#pragma unroll
    for (int off = 32; off; off >>= 1) {
      dot += __shfl_xor(dot, off, 64);
      n1 += __shfl_xor(n1, off, 64);
      n2 += __shfl_xor(n2, off, 64);
    }
    if (lane == 0) {
      float sim = dot / (fmaxf(sqrtf(n1), 1e-12f) * fmaxf(sqrtf(n2), 1e-12f));
      wsum += (sim + 1.0f) * 0.5f;
    }
  }
  if (lane == 0) s_red[wid] = wsum;
  __syncthreads();
  if (tid == 0) part[blockIdx.x] = s_red[0] + s_red[1] + s_red[2] + s_red[3];
}

// ---------------- finalize: ortho + reduce + output ----------------
__global__ __launch_bounds__(256) void k_final(const float* __restrict__ text,
                                               const double* __restrict__ acc,
                                               const float* __restrict__ part,
                                               float* __restrict__ out) {
  __shared__ __align__(16) float s_e[CC * DD];  // 40 KB
  __shared__ float s_red4[4];
  __shared__ double s_red[256];
  const int tid = threadIdx.x, wid = tid >> 6, lane = tid & 63;

  // --- ortho: ||normalize(text) @ normalize(text)^T - I||_F ---
  for (int r = wid; r < CC; r += 4) {
    float4 v[2];
    float ss = 0.f;
#pragma unroll
    for (int c = 0; c < 2; c++) {
      v[c] = *(const float4*)(text + r * DD + c * 256 + lane * 4);
      ss += v[c].x * v[c].x + v[c].y * v[c].y + v[c].z * v[c].z + v[c].w * v[c].w;
    }
    ss = wred(ss);
    float n = fmaxf(sqrtf(ss), 1e-12f);
#pragma unroll
    for (int c = 0; c < 2; c++) {
      float4 w = v[c];
      w.x /= n; w.y /= n; w.z /= n; w.w /= n;
      *(float4*)(&s_e[r * DD + c * 256 + lane * 4]) = w;
    }
  }
  __syncthreads();
  float wss = 0.f;
  for (int p = wid; p < CC * CC; p += 4) {
    const int i = p / CC, j = p % CC;
    float dot = 0.f;
#pragma unroll
    for (int c = 0; c < 2; c++) {
      const int d0 = c * 256 + lane * 4;
      float4 x = *(const float4*)(&s_e[i * DD + d0]);
      float4 y = *(const float4*)(&s_e[j * DD + d0]);
      dot += x.x * y.x + x.y * y.y + x.z * y.z + x.w * y.w;
    }
    dot = wred(dot);
    if (lane == 0) {
      float s = dot - (i == j ? 1.0f : 0.0f);
      wss += s * s;
    }
  }
  if (lane == 0) s_red4[wid] = wss;
  __syncthreads();

  // --- distill partial sum ---
  double s = 0.0;
  for (int i = tid; i < 2048; i += 256) s += (double)part[i];
  s_red[tid] = s;
  __syncthreads();
  for (int st = 128; st; st >>= 1) {
    if (tid < st) s_red[tid] += s_red[tid + st];
    __syncthreads();
  }
  if (tid == 0) {
    double distill = -log(s_red[0] / (double)(BB * TT));
    double act = 0.0, bkg = 0.0;
    for (int b = 0; b < 16; b++) {
      double pa = acc[0 * 16 + b] / 800.0;
      double na = acc[1 * 16 + b] / 800.0;
      double pb = acc[2 * 16 + b] / 800.0;
      double nb = acc[3 * 16 + b] / 800.0;
      act += -(log(pa) + log(1.0 - na));
      bkg += -(log(pb) + log(1.0 - nb));
    }
    act /= 16.0;
    bkg /= 16.0;
    double ortho = sqrt((double)(s_red4[0] + s_red4[1] + s_red4[2] + s_red4[3]));
    double total = distill + act + bkg + ortho;
    out[0] = (float)total;
    out[1] = (float)distill;
    out[2] = (float)act;
    out[3] = (float)bkg;
    out[4] = (float)ortho;
  }
}

extern "C" void kernel_launch(void* const* d_in, const int* in_sizes, int n_in,
                              void* d_out, int out_size, void* d_ws, size_t ws_size,
                              hipStream_t stream) {
  const float* attn = (const float*)d_in[0];
  const float* mu   = (const float*)d_in[1];
  const float* var  = (const float*)d_in[2];
  const float* muc  = (const float*)d_in[3];
  const float* text = (const float*)d_in[4];
  const float* drop = (const float*)d_in[5];
  float* out = (float*)d_out;

  // workspace layout (~30 KB)
  double* acc  = (double*)d_ws;           // 66 doubles: [0..63] kl sums, [64..65] spare
  int* idxb    = (int*)(acc + 66);        // 4*16*40 ints
  float* slogb = (float*)(idxb + 2560);   // 4*16*40 f32
  float* part  = (float*)(slogb + 2560);  // 2048 f32 distill partials

  k_select<<<64, 64, 0, stream>>>(attn, drop, idxb, acc);
  k_slog<<<480, 256, 0, stream>>>(var, idxb, slogb);
  k_kl<<<1280, 256, 0, stream>>>(mu, var, idxb, slogb, acc);
  k_distill<<<2048, 256, 0, stream>>>(mu, muc, part);
  k_final<<<1, 256, 0, stream>>>(text, acc, part, out);
}

// Round 3
// 277.951 us; speedup vs baseline: 1.5311x; 1.2356x over previous
//
#include <hip/hip_runtime.h>
#include <math.h>

// ProbLoss: B=16, T=2048, D=512, C=20. Inputs (f32):
//   d_in[0] attn [B,T,1], d_in[1] mu [B,T,D], d_in[2] var [B,T,D],
//   d_in[3] mu_clip [B,T,D], d_in[4] text_feat [C,D], d_in[5] drop_mask [B,T]
// Output: 5 f32 scalars (total, distill, act_loss, bkg_loss, ortho).

#define BB 16
#define TT 2048
#define DD 512
#define CC 20
#define KEASY 40
#define KHARD 20
#define EPSF 1e-5f

typedef unsigned long long u64;

// ---- DPP wave-64 reductions (VALU-only: ~4cyc/step vs ~120cyc ds ops) ----
template <int CTRL>
__device__ __forceinline__ float dpp_mov(float x) {
  return __int_as_float(__builtin_amdgcn_update_dpp(
      0, __float_as_int(x), CTRL, 0xF, 0xF, true));  // bound_ctrl: 0-fill
}
__device__ __forceinline__ float wsum(float v) {
  v += dpp_mov<0x111>(v);  // row_shr:1
  v += dpp_mov<0x112>(v);  // row_shr:2
  v += dpp_mov<0x114>(v);  // row_shr:4
  v += dpp_mov<0x118>(v);  // row_shr:8
  v += dpp_mov<0x142>(v);  // row_bcast:15
  v += dpp_mov<0x143>(v);  // row_bcast:31
  // total lands in lane 63; broadcast via readlane (uniform, no DS op)
  return __int_as_float(__builtin_amdgcn_readlane(__float_as_int(v), 63));
}
// max-reduce; only used on values >= 0 so the 0-fill is harmless
__device__ __forceinline__ float wmax(float v) {
  v = fmaxf(v, dpp_mov<0x111>(v));
  v = fmaxf(v, dpp_mov<0x112>(v));
  v = fmaxf(v, dpp_mov<0x114>(v));
  v = fmaxf(v, dpp_mov<0x118>(v));
  v = fmaxf(v, dpp_mov<0x142>(v));
  v = fmaxf(v, dpp_mov<0x143>(v));
  return __int_as_float(__builtin_amdgcn_readlane(__float_as_int(v), 63));
}

// count of keys >= mid across the wave's 64x32 keys, via ballot+popcount
// (v_cmp into SGPR pair + s_bcnt1; no cross-lane data movement at all)
__device__ __forceinline__ unsigned cnt_ge(const u64 (&keys)[32], u64 mid) {
  unsigned c = 0;
#pragma unroll
  for (int r = 0; r < 32; r++) c += (unsigned)__popcll(__ballot(keys[r] >= mid));
  return c;  // wave-uniform
}

// k-th largest key via binary search on the 43-bit key space. Keys are
// distinct (low 11 bits = 2047-index) so |{key >= result}| == k exactly.
__device__ __forceinline__ u64 kth_key(const u64 (&keys)[32], unsigned k, u64 hi0) {
  u64 lo = 0, hi = hi0;
  while (lo < hi) {
    u64 mid = lo + ((hi - lo + 1) >> 1);
    if (cnt_ge(keys, mid) >= k) lo = mid; else hi = mid - 1;
  }
  return lo;
}

// =======================================================================
// k1: blocks [0,64) = selection+slog (one wave does the search; 4 waves do
//     slog); blocks [64,2112) = distill. Select blocks first so their serial
//     latency chain overlaps the HBM-bound distill sweep.
// =======================================================================
__global__ __launch_bounds__(256) void k_main1(const float* __restrict__ attn,
                                               const float* __restrict__ drop,
                                               const float* __restrict__ mu,
                                               const float* __restrict__ muc,
                                               const float* __restrict__ var,
                                               int* __restrict__ idxb,
                                               float* __restrict__ slogb,
                                               float* __restrict__ part,
                                               double* __restrict__ acc) {
  const int tid = threadIdx.x, wid = tid >> 6, lane = tid & 63;

  if (blockIdx.x >= 64) {
    // ---------------- distill: (cos(mu,mu_clip)+1)/2 summed ----------------
    __shared__ float s_red[4];
    const int blk = blockIdx.x - 64;
    float wacc = 0.f;
#pragma unroll
    for (int it = 0; it < 4; it++) {
      const int r = blk * 4 + wid + it * 8192;  // covers 0..32767
      const size_t base = (size_t)r * DD;
      float dot = 0.f, n1 = 0.f, n2 = 0.f;
#pragma unroll
      for (int c = 0; c < 2; c++) {
        const int d0 = c * 256 + lane * 4;
        float4 x = *(const float4*)(mu + base + d0);
        float4 y = *(const float4*)(muc + base + d0);
        dot = fmaf(x.x, y.x, fmaf(x.y, y.y, fmaf(x.z, y.z, fmaf(x.w, y.w, dot))));
        n1 = fmaf(x.x, x.x, fmaf(x.y, x.y, fmaf(x.z, x.z, fmaf(x.w, x.w, n1))));
        n2 = fmaf(y.x, y.x, fmaf(y.y, y.y, fmaf(y.z, y.z, fmaf(y.w, y.w, n2))));
      }
      dot = wsum(dot);
      n1 = wsum(n1);
      n2 = wsum(n2);
      if (lane == 0) {
        float sim = dot / (fmaxf(sqrtf(n1), 1e-12f) * fmaxf(sqrtf(n2), 1e-12f));
        wacc += (sim + 1.0f) * 0.5f;
      }
    }
    if (lane == 0) s_red[wid] = wacc;
    __syncthreads();
    if (tid == 0) part[blk] = s_red[0] + s_red[1] + s_red[2] + s_red[3];
    return;
  }

  // ---------------- selection: sel 0: top-40 a*drop; 1: top-40 (max-a)*drop;
  //                  2: top-20 a*inner; 3: top-20 a*outer ----------------
  __shared__ float s_a[TT];
  __shared__ int s_idx[KEASY];
  const int b = blockIdx.x >> 2, sel = blockIdx.x & 3;
  for (int i = tid; i < TT; i += 256) s_a[i] = attn[b * TT + i];
  __syncthreads();

  if (tid < 64) {  // wave 0 only: wave-synchronous search, no barriers
    if (blockIdx.x == 0) {  // zero KL accumulators (ws is re-poisoned)
      acc[lane] = 0.0;
      if (lane < 2) acc[64 + lane] = 0.0;
    }
    const u64 HI0 = (((u64)0x7F800000u) << 11) | 0x7FFull;
    u64 keys[32];
    float med = 0.f, mx = 0.f;
    if (sel >= 2) {
      // median = mean of 1024th/1025th largest values (exact order stats)
#pragma unroll
      for (int r = 0; r < 32; r++) {
        const int i = r * 64 + lane;
        keys[r] = (((u64)__float_as_uint(s_a[i])) << 11) | (u64)(TT - 1 - i);
      }
      const u64 t1 = kth_key(keys, 1024, HI0);
      float cand = 0.f;  // value of largest key < t1 == 1025th largest value
#pragma unroll
      for (int r = 0; r < 32; r++)
        if (keys[r] < t1) cand = fmaxf(cand, __uint_as_float((unsigned)(keys[r] >> 11)));
      med = 0.5f * (__uint_as_float((unsigned)(t1 >> 11)) + wmax(cand));
    }
    if (sel == 1) {
      float m = 0.f;
#pragma unroll
      for (int r = 0; r < 32; r++) m = fmaxf(m, s_a[r * 64 + lane]);
      mx = wmax(m);
    }
#pragma unroll
    for (int r = 0; r < 32; r++) {
      const int i = r * 64 + lane;
      const float a = s_a[i];
      float score;
      if (sel == 0) {
        score = a * drop[b * TT + i];
      } else if (sel == 1) {
        score = (mx - a) * drop[b * TT + i];
      } else {
        bool sall = true, ball = true, sany = false, bany = false;
#pragma unroll
        for (int o = -3; o <= 3; o++) {
          const int t = i + o;
          const bool one = (t >= 0 && t < TT) ? (s_a[t] > med) : false;  // 0-pad
          if (o >= -1 && o <= 1) { sall = sall && one; sany = sany || one; }
          ball = ball && one;
          bany = bany || one;
        }
        score = (sel == 2) ? ((sall && !ball) ? a : 0.f)    // er3 && !er7
                           : ((bany && !sany) ? a : 0.f);   // dl7 && !dl3
      }
      // score >= +0 so float bits compare monotonically
      keys[r] = (((u64)__float_as_uint(score)) << 11) | (u64)(TT - 1 - i);
    }
    const unsigned K = (sel < 2) ? KEASY : KHARD;
    const u64 T = kth_key(keys, K, HI0);
    // compact-write selected indices via ballot prefix-popcount
    unsigned base = 0;
    const u64 lmask = (1ull << lane) - 1;
    int* dst = idxb + sel * (BB * KEASY) + b * KEASY;
#pragma unroll
    for (int r = 0; r < 32; r++) {
      const u64 bal = __ballot(keys[r] >= T);
      if (keys[r] >= T) {
        const unsigned pos = base + (unsigned)__popcll(bal & lmask);
        dst[pos] = r * 64 + lane;
        s_idx[pos] = r * 64 + lane;
      }
      base += (unsigned)__popcll(bal);
    }
  }
  __syncthreads();

  // slog for this block's selected rows: sum_d log(var+eps), 4 waves
  const int Ksel = (sel < 2) ? KEASY : KHARD;
  for (int j = wid; j < Ksel; j += 4) {
    const int t = s_idx[j];
    const float* row = var + ((size_t)b * TT + t) * DD;
    float a2 = 0.f;
#pragma unroll
    for (int c = 0; c < 2; c++) {
      float4 v = *(const float4*)(row + c * 256 + lane * 4);
      a2 += __logf(v.x + EPSF) + __logf(v.y + EPSF) +
            __logf(v.z + EPSF) + __logf(v.w + EPSF);
    }
    a2 = wsum(a2);
    if (lane == 0) slogb[sel * 640 + b * 40 + j] = a2;
  }
}

// =======================================================================
// k2: KL. One block per (klid, b, ip); 40 q's split over 4 waves.
// klid0: p=hard_act(2) q=easy_act(0); klid1: p=hard_act q=easy_bkg(1)
// klid2: p=hard_bkg(3) q=easy_bkg;    klid3: p=hard_bkg q=easy_act
// =======================================================================
__global__ __launch_bounds__(256) void k_kl(const float* __restrict__ mu,
                                            const float* __restrict__ var,
                                            const int* __restrict__ idxb,
                                            const float* __restrict__ slogb,
                                            double* __restrict__ acc) {
  __shared__ __align__(16) float s_mup[DD];
  __shared__ __align__(16) float s_cvp[DD];
  __shared__ float s_red[4];
  const int blk = blockIdx.x;
  const int klid = blk / 320, rem = blk % 320, b = rem / 20, ip = rem % 20;
  const int psel = (klid < 2) ? 2 : 3;
  const int qsel = (klid == 0) ? 0 : (klid == 1) ? 1 : (klid == 2) ? 1 : 0;
  const int tid = threadIdx.x, wid = tid >> 6, lane = tid & 63;
  const int pidx = idxb[psel * 640 + b * 40 + ip];
  const float slog_p = slogb[psel * 640 + b * 40 + ip];
  const size_t pbase = ((size_t)b * TT + pidx) * DD;
  for (int i = tid; i < DD; i += 256) {
    s_mup[i] = mu[pbase + i];
    s_cvp[i] = var[pbase + i] + EPSF;
  }
  __syncthreads();
  float wacc = 0.f;
  for (int iq = wid; iq < KEASY; iq += 4) {
    const int qidx = idxb[qsel * 640 + b * 40 + iq];
    const float slog_q = slogb[qsel * 640 + b * 40 + iq];
    const size_t qbase = ((size_t)b * TT + qidx) * DD;
    float a1 = 0.f, a3 = 0.f;
#pragma unroll
    for (int c = 0; c < 2; c++) {
      const int d0 = c * 256 + lane * 4;
      float4 mq = *(const float4*)(mu + qbase + d0);
      float4 vq = *(const float4*)(var + qbase + d0);
      float4 mp = *(const float4*)(&s_mup[d0]);
      float4 cp = *(const float4*)(&s_cvp[d0]);
      { float r = 1.0f / (vq.x + EPSF); float df = mq.x - mp.x; a1 += df * df * r; a3 += cp.x * r; }
      { float r = 1.0f / (vq.y + EPSF); float df = mq.y - mp.y; a1 += df * df * r; a3 += cp.y * r; }
      { float r = 1.0f / (vq.z + EPSF); float df = mq.z - mp.z; a1 += df * df * r; a3 += cp.z * r; }
      { float r = 1.0f / (vq.w + EPSF); float df = mq.w - mp.w; a1 += df * df * r; a3 += cp.w * r; }
    }
    a1 = wsum(a1);
    a3 = wsum(a3);
    if (lane == 0) {
      float dist = 0.5f * a1 + 0.5f * (slog_q - slog_p) + 0.5f * a3 - 0.5f * (float)DD;
      wacc += 1.0f / (dist + 1.0f);
    }
  }
  if (lane == 0) s_red[wid] = wacc;
  __syncthreads();
  if (tid == 0) {
    double sum = (double)s_red[0] + s_red[1] + s_red[2] + s_red[3];
    atomicAdd(&acc[klid * 16 + b], sum);
  }
}

// =======================================================================
// k3: ortho + final reduction + output
// =======================================================================
__global__ __launch_bounds__(256) void k_final(const float* __restrict__ text,
                                               const double* __restrict__ acc,
                                               const float* __restrict__ part,
                                               float* __restrict__ out) {
  __shared__ __align__(16) float s_e[CC * DD];  // 40 KB
  __shared__ float s_red4[4];
  __shared__ double s_red[256];
  const int tid = threadIdx.x, wid = tid >> 6, lane = tid & 63;

  // --- ortho: ||normalize(text) @ normalize(text)^T - I||_F ---
  for (int r = wid; r < CC; r += 4) {
    float4 v[2];
    float ss = 0.f;
#pragma unroll
    for (int c = 0; c < 2; c++) {
      v[c] = *(const float4*)(text + r * DD + c * 256 + lane * 4);
      ss += v[c].x * v[c].x + v[c].y * v[c].y + v[c].z * v[c].z + v[c].w * v[c].w;
    }
    ss = wsum(ss);
    const float n = fmaxf(sqrtf(ss), 1e-12f);
#pragma unroll
    for (int c = 0; c < 2; c++) {
      float4 w = v[c];
      w.x /= n; w.y /= n; w.z /= n; w.w /= n;
      *(float4*)(&s_e[r * DD + c * 256 + lane * 4]) = w;
    }
  }
  __syncthreads();
  float wss = 0.f;
  for (int p = wid; p < CC * CC; p += 4) {
    const int i = p / CC, j = p % CC;
    float dot = 0.f;
#pragma unroll
    for (int c = 0; c < 2; c++) {
      const int d0 = c * 256 + lane * 4;
      float4 x = *(const float4*)(&s_e[i * DD + d0]);
      float4 y = *(const float4*)(&s_e[j * DD + d0]);
      dot += x.x * y.x + x.y * y.y + x.z * y.z + x.w * y.w;
    }
    dot = wsum(dot);
    if (lane == 0) {
      const float s = dot - (i == j ? 1.0f : 0.0f);
      wss += s * s;
    }
  }
  if (lane == 0) s_red4[wid] = wss;
  __syncthreads();

  // --- distill partial sum + scalar epilogue ---
  double s = 0.0;
  for (int i = tid; i < 2048; i += 256) s += (double)part[i];
  s_red[tid] = s;
  __syncthreads();
  for (int st = 128; st; st >>= 1) {
    if (tid < st) s_red[tid] += s_red[tid + st];
    __syncthreads();
  }
  if (tid == 0) {
    const double distill = -log(s_red[0] / (double)(BB * TT));
    double act = 0.0, bkg = 0.0;
    for (int b = 0; b < 16; b++) {
      const double pa = acc[0 * 16 + b] / 800.0;
      const double na = acc[1 * 16 + b] / 800.0;
      const double pb = acc[2 * 16 + b] / 800.0;
      const double nb = acc[3 * 16 + b] / 800.0;
      act += -(log(pa) + log(1.0 - na));
      bkg += -(log(pb) + log(1.0 - nb));
    }
    act /= 16.0;
    bkg /= 16.0;
    const double ortho = sqrt((double)(s_red4[0] + s_red4[1] + s_red4[2] + s_red4[3]));
    const double total = distill + act + bkg + ortho;
    out[0] = (float)total;
    out[1] = (float)distill;
    out[2] = (float)act;
    out[3] = (float)bkg;
    out[4] = (float)ortho;
  }
}

extern "C" void kernel_launch(void* const* d_in, const int* in_sizes, int n_in,
                              void* d_out, int out_size, void* d_ws, size_t ws_size,
                              hipStream_t stream) {
  const float* attn = (const float*)d_in[0];
  const float* mu   = (const float*)d_in[1];
  const float* var  = (const float*)d_in[2];
  const float* muc  = (const float*)d_in[3];
  const float* text = (const float*)d_in[4];
  const float* drop = (const float*)d_in[5];
  float* out = (float*)d_out;

  // workspace layout (~30 KB)
  double* acc  = (double*)d_ws;           // 66 doubles: [0..63] kl sums
  int* idxb    = (int*)(acc + 66);        // 4*16*40 ints
  float* slogb = (float*)(idxb + 2560);   // 4*16*40 f32
  float* part  = (float*)(slogb + 2560);  // 2048 f32 distill partials

  k_main1<<<2112, 256, 0, stream>>>(attn, drop, mu, muc, var, idxb, slogb, part, acc);
  k_kl<<<1280, 256, 0, stream>>>(mu, var, idxb, slogb, acc);
  k_final<<<1, 256, 0, stream>>>(text, acc, part, out);
}

// Round 4
// 274.683 us; speedup vs baseline: 1.5493x; 1.0119x over previous
//
#include <hip/hip_runtime.h>
#include <math.h>

// ProbLoss: B=16, T=2048, D=512, C=20. Inputs (f32):
//   d_in[0] attn [B,T,1], d_in[1] mu [B,T,D], d_in[2] var [B,T,D],
//   d_in[3] mu_clip [B,T,D], d_in[4] text_feat [C,D], d_in[5] drop_mask [B,T]
// Output: 5 f32 scalars (total, distill, act_loss, bkg_loss, ortho).

#define BB 16
#define TT 2048
#define DD 512
#define CC 20
#define KEASY 40
#define KHARD 20
#define EPSF 1e-5f

typedef unsigned long long u64;

// ---- DPP wave-64 reductions (VALU-only) ----
template <int CTRL>
__device__ __forceinline__ float dpp_mov(float x) {
  return __int_as_float(__builtin_amdgcn_update_dpp(
      0, __float_as_int(x), CTRL, 0xF, 0xF, true));  // bound_ctrl: 0-fill
}
__device__ __forceinline__ float wsum63(float v) {  // total valid in lane 63
  v += dpp_mov<0x111>(v);
  v += dpp_mov<0x112>(v);
  v += dpp_mov<0x114>(v);
  v += dpp_mov<0x118>(v);
  v += dpp_mov<0x142>(v);
  v += dpp_mov<0x143>(v);
  return v;
}
__device__ __forceinline__ float wsum_bc(float v) {  // broadcast to all lanes
  return __int_as_float(__builtin_amdgcn_readlane(__float_as_int(wsum63(v)), 63));
}
__device__ __forceinline__ float wmax_bc(float v) {  // nonneg values only
  v = fmaxf(v, dpp_mov<0x111>(v));
  v = fmaxf(v, dpp_mov<0x112>(v));
  v = fmaxf(v, dpp_mov<0x114>(v));
  v = fmaxf(v, dpp_mov<0x118>(v));
  v = fmaxf(v, dpp_mov<0x142>(v));
  v = fmaxf(v, dpp_mov<0x143>(v));
  return __int_as_float(__builtin_amdgcn_readlane(__float_as_int(v), 63));
}

// k-th largest VALUE (order statistic with multiplicity) among the wave's
// 64x32 nonneg floats: binary search on float-bit space. v_cmp+ballot+
// s_bcnt1 only -- counts are wave-uniform, no cross-lane data movement, no
// LDS, and only 32 VGPRs live. (Round-3's u64 keys[32] needed 64 VGPRs and
// spilled to scratch: WRITE_SIZE 83 MB, 80 us. This is the fix.)
__device__ __forceinline__ float kth_val(const float (&v)[32], unsigned k, unsigned hi) {
  unsigned lo = 0;
  while (lo < hi) {
    const unsigned mid = lo + ((hi - lo + 1) >> 1);
    const float mf = __uint_as_float(mid);
    unsigned c = 0;
#pragma unroll
    for (int r = 0; r < 32; r++) c += (unsigned)__popcll(__ballot(v[r] >= mf));
    if (c >= k) lo = mid; else hi = mid - 1;
  }
  return __uint_as_float(lo);
}

// =======================================================================
// k1: blocks [0,64) = selection+slog; blocks [64,2112) = distill.
// Select blocks scheduled first so their serial search chain hides under
// the HBM-bound distill sweep.
// =======================================================================
__global__ __launch_bounds__(256) void k_main1(const float* __restrict__ attn,
                                               const float* __restrict__ drop,
                                               const float* __restrict__ mu,
                                               const float* __restrict__ muc,
                                               const float* __restrict__ var,
                                               int* __restrict__ idxb,
                                               float* __restrict__ slogb,
                                               float* __restrict__ part,
                                               double* __restrict__ acc) {
  const int tid = threadIdx.x, wid = tid >> 6, lane = tid & 63;

  if (blockIdx.x >= 64) {
    // ---------------- distill: (cos(mu,mu_clip)+1)/2 summed ----------------
    // 2-stage pipeline: row it+1's 4 float4 loads issued before row it's
    // DPP reduce, so VMEM latency overlaps the reduce chain.
    __shared__ float s_red[4];
    const int blk = blockIdx.x - 64;
    const float* pmu = mu + (size_t)(blk * 4 + wid) * DD + lane * 4;
    const float* pmc = muc + (size_t)(blk * 4 + wid) * DD + lane * 4;
    float4 xa = *(const float4*)(pmu);
    float4 xb = *(const float4*)(pmu + 256);
    float4 ya = *(const float4*)(pmc);
    float4 yb = *(const float4*)(pmc + 256);
    float wacc = 0.f;
#pragma unroll
    for (int it = 0; it < 4; it++) {  // rows r, r+8192, r+16384, r+24576
      const float4 cxa = xa, cxb = xb, cya = ya, cyb = yb;
      if (it < 3) {
        const size_t off = (size_t)(it + 1) * 8192 * DD;
        xa = *(const float4*)(pmu + off);
        xb = *(const float4*)(pmu + off + 256);
        ya = *(const float4*)(pmc + off);
        yb = *(const float4*)(pmc + off + 256);
      }
      float dot = 0.f, n1 = 0.f, n2 = 0.f;
      dot = fmaf(cxa.x, cya.x, fmaf(cxa.y, cya.y, fmaf(cxa.z, cya.z, fmaf(cxa.w, cya.w, dot))));
      n1 = fmaf(cxa.x, cxa.x, fmaf(cxa.y, cxa.y, fmaf(cxa.z, cxa.z, fmaf(cxa.w, cxa.w, n1))));
      n2 = fmaf(cya.x, cya.x, fmaf(cya.y, cya.y, fmaf(cya.z, cya.z, fmaf(cya.w, cya.w, n2))));
      dot = fmaf(cxb.x, cyb.x, fmaf(cxb.y, cyb.y, fmaf(cxb.z, cyb.z, fmaf(cxb.w, cyb.w, dot))));
      n1 = fmaf(cxb.x, cxb.x, fmaf(cxb.y, cxb.y, fmaf(cxb.z, cxb.z, fmaf(cxb.w, cxb.w, n1))));
      n2 = fmaf(cyb.x, cyb.x, fmaf(cyb.y, cyb.y, fmaf(cyb.z, cyb.z, fmaf(cyb.w, cyb.w, n2))));
      dot = wsum63(dot);
      n1 = wsum63(n1);
      n2 = wsum63(n2);
      if (lane == 63) {
        const float sim = dot / (fmaxf(sqrtf(n1), 1e-12f) * fmaxf(sqrtf(n2), 1e-12f));
        wacc += (sim + 1.0f) * 0.5f;
      }
    }
    if (lane == 63) s_red[wid] = wacc;
    __syncthreads();
    if (tid == 0) part[blk] = s_red[0] + s_red[1] + s_red[2] + s_red[3];
    return;
  }

  // ---------------- selection: sel 0: top-40 a*drop; 1: top-40 (max-a)*drop;
  //                  2: top-20 a*inner; 3: top-20 a*outer ----------------
  __shared__ float s_a[TT];
  __shared__ int s_idx[KEASY];
  const int b = blockIdx.x >> 2, sel = blockIdx.x & 3;
  for (int i = tid; i < TT; i += 256) s_a[i] = attn[b * TT + i];
  __syncthreads();

  if (tid < 64) {  // wave 0 only: wave-synchronous, no barriers
    if (blockIdx.x == 0) acc[lane] = 0.0;  // zero KL accumulators (ws poisoned)
    float v[32];
    float med = 0.f, mx = 0.f;
    if (sel >= 2) {
      // median = mean of 1024th/1025th largest values (exact order stats;
      // ties don't affect the order-stat VALUE). attn ~ U[0,1) so hi=1.0f.
#pragma unroll
      for (int r = 0; r < 32; r++) v[r] = s_a[r * 64 + lane];
      const float v1 = kth_val(v, 1024, 0x3F800000u);
      const float v2 = kth_val(v, 1025, __float_as_uint(v1));
      med = 0.5f * (v1 + v2);
    }
    if (sel == 1) {
      float m = 0.f;
#pragma unroll
      for (int r = 0; r < 32; r++) m = fmaxf(m, s_a[r * 64 + lane]);
      mx = wmax_bc(m);
    }
    // scores overwrite v[] in place (neighborhood reads come from s_a)
#pragma unroll
    for (int r = 0; r < 32; r++) {
      const int i = r * 64 + lane;
      const float a = s_a[i];
      float score;
      if (sel == 0) {
        score = a * drop[b * TT + i];
      } else if (sel == 1) {
        score = (mx - a) * drop[b * TT + i];
      } else {
        bool sall = true, ball = true, sany = false, bany = false;
#pragma unroll
        for (int o = -3; o <= 3; o++) {
          const int t = i + o;
          const bool one = (t >= 0 && t < TT) ? (s_a[t] > med) : false;  // 0-pad
          if (o >= -1 && o <= 1) { sall = sall && one; sany = sany || one; }
          ball = ball && one;
          bany = bany || one;
        }
        score = (sel == 2) ? ((sall && !ball) ? a : 0.f)    // er3 && !er7
                           : ((bany && !sany) ? a : 0.f);   // dl7 && !dl3
      }
      v[r] = score;
    }
    const unsigned K = (sel < 2) ? KEASY : KHARD;
    const unsigned hiS = (sel < 2) ? 0x40200000u : 0x3F800000u;  // 2.5 / 1.0
    const float ss = kth_val(v, K, hiS);  // exact element value (k-th largest)
    // JAX stable top-k set: all (score > ss) plus the (K - c_gt) smallest-
    // index elements with score == ss.
    unsigned cgt = 0;
#pragma unroll
    for (int r = 0; r < 32; r++) cgt += (unsigned)__popcll(__ballot(v[r] > ss));
    unsigned need = K - cgt;
    unsigned base = 0;
    const u64 lmask = (1ull << lane) - 1;
    int* dst = idxb + sel * (BB * KEASY) + b * KEASY;
#pragma unroll
    for (int r = 0; r < 32; r++) {
      const bool gt = v[r] > ss;
      const bool eq = v[r] == ss;
      const u64 beq = __ballot(eq);
      const unsigned neq = (unsigned)__popcll(beq);
      const unsigned take = (need < neq) ? need : neq;
      const bool tk = eq && ((unsigned)__popcll(beq & lmask) < take);
      const u64 bsel = __ballot(gt || tk);
      if (gt || tk) {
        const unsigned pos = base + (unsigned)__popcll(bsel & lmask);
        dst[pos] = r * 64 + lane;
        s_idx[pos] = r * 64 + lane;
      }
      base += (unsigned)__popcll(bsel);
      need -= take;
    }
  }
  __syncthreads();

  // slog for this block's selected rows: sum_d log(var+eps), 4 waves
  const int Ksel = (sel < 2) ? KEASY : KHARD;
  for (int j = wid; j < Ksel; j += 4) {
    const int t = s_idx[j];
    const float* row = var + ((size_t)b * TT + t) * DD;
    float a2 = 0.f;
#pragma unroll
    for (int c = 0; c < 2; c++) {
      float4 vv = *(const float4*)(row + c * 256 + lane * 4);
      a2 += __logf(vv.x + EPSF) + __logf(vv.y + EPSF) +
            __logf(vv.z + EPSF) + __logf(vv.w + EPSF);
    }
    a2 = wsum63(a2);
    if (lane == 63) slogb[sel * 640 + b * 40 + j] = a2;
  }
}

// =======================================================================
// k2: KL. One block per (klid, b, ip); 40 q's over 4 waves, 2 q's in
// flight per wave (independent load->reduce chains halve serial latency).
// klid0: p=hard_act(2) q=easy_act(0); klid1: p=hard_act q=easy_bkg(1)
// klid2: p=hard_bkg(3) q=easy_bkg;    klid3: p=hard_bkg q=easy_act
// =======================================================================
__global__ __launch_bounds__(256) void k_kl(const float* __restrict__ mu,
                                            const float* __restrict__ var,
                                            const int* __restrict__ idxb,
                                            const float* __restrict__ slogb,
                                            double* __restrict__ acc) {
  __shared__ __align__(16) float s_mup[DD];
  __shared__ __align__(16) float s_cvp[DD];
  __shared__ float s_red[4];
  const int blk = blockIdx.x;
  const int klid = blk / 320, rem = blk % 320, b = rem / 20, ip = rem % 20;
  const int psel = (klid < 2) ? 2 : 3;
  const int qsel = (klid == 0) ? 0 : (klid == 1) ? 1 : (klid == 2) ? 1 : 0;
  const int tid = threadIdx.x, wid = tid >> 6, lane = tid & 63;
  const int pidx = idxb[psel * 640 + b * 40 + ip];
  const float slog_p = slogb[psel * 640 + b * 40 + ip];
  const size_t pbase = ((size_t)b * TT + pidx) * DD;
  for (int i = tid; i < DD; i += 256) {
    s_mup[i] = mu[pbase + i];
    s_cvp[i] = var[pbase + i] + EPSF;
  }
  __syncthreads();
  float wacc = 0.f;
#pragma unroll
  for (int t = 0; t < 5; t++) {
    const int iqA = wid + 8 * t, iqB = iqA + 4;
    const int qA = idxb[qsel * 640 + b * 40 + iqA];
    const int qB = idxb[qsel * 640 + b * 40 + iqB];
    const float slqA = slogb[qsel * 640 + b * 40 + iqA];
    const float slqB = slogb[qsel * 640 + b * 40 + iqB];
    const size_t baA = ((size_t)b * TT + qA) * DD;
    const size_t baB = ((size_t)b * TT + qB) * DD;
    float a1A = 0.f, a3A = 0.f, a1B = 0.f, a3B = 0.f;
#pragma unroll
    for (int c = 0; c < 2; c++) {
      const int d0 = c * 256 + lane * 4;
      const float4 mqA = *(const float4*)(mu + baA + d0);
      const float4 vqA = *(const float4*)(var + baA + d0);
      const float4 mqB = *(const float4*)(mu + baB + d0);
      const float4 vqB = *(const float4*)(var + baB + d0);
      const float4 mp = *(const float4*)(&s_mup[d0]);
      const float4 cp = *(const float4*)(&s_cvp[d0]);
      { float r = 1.0f / (vqA.x + EPSF); float df = mqA.x - mp.x; a1A += df * df * r; a3A += cp.x * r; }
      { float r = 1.0f / (vqA.y + EPSF); float df = mqA.y - mp.y; a1A += df * df * r; a3A += cp.y * r; }
      { float r = 1.0f / (vqA.z + EPSF); float df = mqA.z - mp.z; a1A += df * df * r; a3A += cp.z * r; }
      { float r = 1.0f / (vqA.w + EPSF); float df = mqA.w - mp.w; a1A += df * df * r; a3A += cp.w * r; }
      { float r = 1.0f / (vqB.x + EPSF); float df = mqB.x - mp.x; a1B += df * df * r; a3B += cp.x * r; }
      { float r = 1.0f / (vqB.y + EPSF); float df = mqB.y - mp.y; a1B += df * df * r; a3B += cp.y * r; }
      { float r = 1.0f / (vqB.z + EPSF); float df = mqB.z - mp.z; a1B += df * df * r; a3B += cp.z * r; }
      { float r = 1.0f / (vqB.w + EPSF); float df = mqB.w - mp.w; a1B += df * df * r; a3B += cp.w * r; }
    }
    a1A = wsum63(a1A);
    a3A = wsum63(a3A);
    a1B = wsum63(a1B);
    a3B = wsum63(a3B);
    if (lane == 63) {
      const float dA = 0.5f * a1A + 0.5f * (slqA - slog_p) + 0.5f * a3A - 256.0f;
      const float dB = 0.5f * a1B + 0.5f * (slqB - slog_p) + 0.5f * a3B - 256.0f;
      wacc += 1.0f / (dA + 1.0f) + 1.0f / (dB + 1.0f);
    }
  }
  if (lane == 63) s_red[wid] = wacc;
  __syncthreads();
  if (tid == 0) {
    const double sum = (double)s_red[0] + s_red[1] + s_red[2] + s_red[3];
    atomicAdd(&acc[klid * 16 + b], sum);
  }
}

// =======================================================================
// k3: ortho + final reduction + output (1 block; serial tail)
// =======================================================================
__global__ __launch_bounds__(256) void k_final(const float* __restrict__ text,
                                               const double* __restrict__ acc,
                                               const float* __restrict__ part,
                                               float* __restrict__ out) {
  __shared__ __align__(16) float s_e[CC * DD];  // 40 KB
  __shared__ float s_red4[4];
  __shared__ double s_red[256];
  const int tid = threadIdx.x, wid = tid >> 6, lane = tid & 63;

  // --- ortho: ||normalize(text) @ normalize(text)^T - I||_F ---
  for (int r = wid; r < CC; r += 4) {
    float4 v[2];
    float ss = 0.f;
#pragma unroll
    for (int c = 0; c < 2; c++) {
      v[c] = *(const float4*)(text + r * DD + c * 256 + lane * 4);
      ss += v[c].x * v[c].x + v[c].y * v[c].y + v[c].z * v[c].z + v[c].w * v[c].w;
    }
    ss = wsum_bc(ss);
    const float n = fmaxf(sqrtf(ss), 1e-12f);
#pragma unroll
    for (int c = 0; c < 2; c++) {
      float4 w = v[c];
      w.x /= n; w.y /= n; w.z /= n; w.w /= n;
      *(float4*)(&s_e[r * DD + c * 256 + lane * 4]) = w;
    }
  }
  __syncthreads();
  float wss = 0.f;
  for (int p = wid; p < CC * CC; p += 4) {
    const int i = p / CC, j = p % CC;
    float dot = 0.f;
#pragma unroll
    for (int c = 0; c < 2; c++) {
      const int d0 = c * 256 + lane * 4;
      const float4 x = *(const float4*)(&s_e[i * DD + d0]);
      const float4 y = *(const float4*)(&s_e[j * DD + d0]);
      dot += x.x * y.x + x.y * y.y + x.z * y.z + x.w * y.w;
    }
    dot = wsum63(dot);
    if (lane == 63) {
      const float s = dot - (i == j ? 1.0f : 0.0f);
      wss += s * s;
    }
  }
  if (lane == 63) s_red4[wid] = wss;
  __syncthreads();

  // --- distill partial sum + scalar epilogue ---
  double s = 0.0;
  for (int i = tid; i < 2048; i += 256) s += (double)part[i];
  s_red[tid] = s;
  __syncthreads();
  for (int st = 128; st; st >>= 1) {
    if (tid < st) s_red[tid] += s_red[tid + st];
    __syncthreads();
  }
  if (tid == 0) {
    const double distill = -log(s_red[0] / (double)(BB * TT));
    double act = 0.0, bkg = 0.0;
    for (int b = 0; b < 16; b++) {
      const double pa = acc[0 * 16 + b] / 800.0;
      const double na = acc[1 * 16 + b] / 800.0;
      const double pb = acc[2 * 16 + b] / 800.0;
      const double nb = acc[3 * 16 + b] / 800.0;
      act += -(log(pa) + log(1.0 - na));
      bkg += -(log(pb) + log(1.0 - nb));
    }
    act /= 16.0;
    bkg /= 16.0;
    const double ortho = sqrt((double)(s_red4[0] + s_red4[1] + s_red4[2] + s_red4[3]));
    const double total = distill + act + bkg + ortho;
    out[0] = (float)total;
    out[1] = (float)distill;
    out[2] = (float)act;
    out[3] = (float)bkg;
    out[4] = (float)ortho;
  }
}

extern "C" void kernel_launch(void* const* d_in, const int* in_sizes, int n_in,
                              void* d_out, int out_size, void* d_ws, size_t ws_size,
                              hipStream_t stream) {
  const float* attn = (const float*)d_in[0];
  const float* mu   = (const float*)d_in[1];
  const float* var  = (const float*)d_in[2];
  const float* muc  = (const float*)d_in[3];
  const float* text = (const float*)d_in[4];
  const float* drop = (const float*)d_in[5];
  float* out = (float*)d_out;

  // workspace layout (~30 KB)
  double* acc  = (double*)d_ws;           // 64 doubles: kl sums
  int* idxb    = (int*)(acc + 66);        // 4*16*40 ints
  float* slogb = (float*)(idxb + 2560);   // 4*16*40 f32
  float* part  = (float*)(slogb + 2560);  // 2048 f32 distill partials

  k_main1<<<2112, 256, 0, stream>>>(attn, drop, mu, muc, var, idxb, slogb, part, acc);
  k_kl<<<1280, 256, 0, stream>>>(mu, var, idxb, slogb, acc);
  k_final<<<1, 256, 0, stream>>>(text, acc, part, out);
}

// Round 5
// 269.827 us; speedup vs baseline: 1.5772x; 1.0180x over previous
//
#include <hip/hip_runtime.h>
#include <math.h>

// ProbLoss: B=16, T=2048, D=512, C=20. Inputs (f32):
//   d_in[0] attn [B,T,1], d_in[1] mu [B,T,D], d_in[2] var [B,T,D],
//   d_in[3] mu_clip [B,T,D], d_in[4] text_feat [C,D], d_in[5] drop_mask [B,T]
// Output: 5 f32 scalars (total, distill, act_loss, bkg_loss, ortho).

#define BB 16
#define TT 2048
#define DD 512
#define CC 20
#define KEASY 40
#define KHARD 20
#define EPSF 1e-5f

typedef unsigned long long u64;

// ---- DPP wave-64 reductions (VALU-only) ----
template <int CTRL>
__device__ __forceinline__ float dpp_mov(float x) {
  return __int_as_float(__builtin_amdgcn_update_dpp(
      0, __float_as_int(x), CTRL, 0xF, 0xF, true));  // bound_ctrl: 0-fill
}
__device__ __forceinline__ float wsum63(float v) {  // total valid in lane 63
  v += dpp_mov<0x111>(v);
  v += dpp_mov<0x112>(v);
  v += dpp_mov<0x114>(v);
  v += dpp_mov<0x118>(v);
  v += dpp_mov<0x142>(v);
  v += dpp_mov<0x143>(v);
  return v;
}
__device__ __forceinline__ float wsum_bc(float v) {  // broadcast to all lanes
  return __int_as_float(__builtin_amdgcn_readlane(__float_as_int(wsum63(v)), 63));
}
__device__ __forceinline__ float wmax_bc(float v) {  // nonneg values only
  v = fmaxf(v, dpp_mov<0x111>(v));
  v = fmaxf(v, dpp_mov<0x112>(v));
  v = fmaxf(v, dpp_mov<0x114>(v));
  v = fmaxf(v, dpp_mov<0x118>(v));
  v = fmaxf(v, dpp_mov<0x142>(v));
  v = fmaxf(v, dpp_mov<0x143>(v));
  return __int_as_float(__builtin_amdgcn_readlane(__float_as_int(v), 63));
}

// k-th largest VALUE (order statistic with multiplicity) among the wave's
// 64x32 nonneg floats: binary search on float-bit space. v_cmp+ballot+
// s_bcnt1 only -- wave-uniform counts, no cross-lane data movement, no LDS.
__device__ __forceinline__ float kth_val(const float (&v)[32], unsigned k, unsigned hi) {
  unsigned lo = 0;
  while (lo < hi) {
    const unsigned mid = lo + ((hi - lo + 1) >> 1);
    const float mf = __uint_as_float(mid);
    unsigned c = 0;
#pragma unroll
    for (int r = 0; r < 32; r++) c += (unsigned)__popcll(__ballot(v[r] >= mf));
    if (c >= k) lo = mid; else hi = mid - 1;
  }
  return __uint_as_float(lo);
}

// =======================================================================
// k1: blocks [0,64) = selection+slog; blocks [64,2112) = distill.
// __launch_bounds__(256, 1): round-4's plain (256) let the allocator target
// 32 VGPRs and spill BOTH paths to scratch (WRITE_SIZE 83 MB, 80 us).
// =======================================================================
__global__ __launch_bounds__(256, 1) void k_main1(const float* __restrict__ attn,
                                                  const float* __restrict__ drop,
                                                  const float* __restrict__ mu,
                                                  const float* __restrict__ muc,
                                                  const float* __restrict__ var,
                                                  int* __restrict__ idxb,
                                                  float* __restrict__ slogb,
                                                  float* __restrict__ part,
                                                  double* __restrict__ acc) {
  const int tid = threadIdx.x, wid = tid >> 6, lane = tid & 63;

  if (blockIdx.x >= 64) {
    // ---------------- distill: (cos(mu,mu_clip)+1)/2 summed ----------------
    __shared__ float s_red[4];
    const int blk = blockIdx.x - 64;
    const float* pmu = mu + (size_t)(blk * 4 + wid) * DD + lane * 4;
    const float* pmc = muc + (size_t)(blk * 4 + wid) * DD + lane * 4;
    float4 xa = *(const float4*)(pmu);
    float4 xb = *(const float4*)(pmu + 256);
    float4 ya = *(const float4*)(pmc);
    float4 yb = *(const float4*)(pmc + 256);
    float wacc = 0.f;
#pragma unroll
    for (int it = 0; it < 4; it++) {  // rows r, r+8192, r+16384, r+24576
      const float4 cxa = xa, cxb = xb, cya = ya, cyb = yb;
      if (it < 3) {
        const size_t off = (size_t)(it + 1) * 8192 * DD;
        xa = *(const float4*)(pmu + off);
        xb = *(const float4*)(pmu + off + 256);
        ya = *(const float4*)(pmc + off);
        yb = *(const float4*)(pmc + off + 256);
      }
      float dot = 0.f, n1 = 0.f, n2 = 0.f;
      dot = fmaf(cxa.x, cya.x, fmaf(cxa.y, cya.y, fmaf(cxa.z, cya.z, fmaf(cxa.w, cya.w, dot))));
      n1 = fmaf(cxa.x, cxa.x, fmaf(cxa.y, cxa.y, fmaf(cxa.z, cxa.z, fmaf(cxa.w, cxa.w, n1))));
      n2 = fmaf(cya.x, cya.x, fmaf(cya.y, cya.y, fmaf(cya.z, cya.z, fmaf(cya.w, cya.w, n2))));
      dot = fmaf(cxb.x, cyb.x, fmaf(cxb.y, cyb.y, fmaf(cxb.z, cyb.z, fmaf(cxb.w, cyb.w, dot))));
      n1 = fmaf(cxb.x, cxb.x, fmaf(cxb.y, cxb.y, fmaf(cxb.z, cxb.z, fmaf(cxb.w, cxb.w, n1))));
      n2 = fmaf(cyb.x, cyb.x, fmaf(cyb.y, cyb.y, fmaf(cyb.z, cyb.z, fmaf(cyb.w, cyb.w, n2))));
      dot = wsum63(dot);
      n1 = wsum63(n1);
      n2 = wsum63(n2);
      if (lane == 63) {
        const float sim = dot / (fmaxf(sqrtf(n1), 1e-12f) * fmaxf(sqrtf(n2), 1e-12f));
        wacc += (sim + 1.0f) * 0.5f;
      }
    }
    if (lane == 63) s_red[wid] = wacc;
    __syncthreads();
    if (tid == 0) part[blk] = s_red[0] + s_red[1] + s_red[2] + s_red[3];
    return;
  }

  // ---------------- selection: sel 0: top-40 a*drop; 1: top-40 (max-a)*drop;
  //                  2: top-20 a*inner; 3: top-20 a*outer ----------------
  __shared__ float s_a[TT];
  __shared__ int s_idx[KEASY];
  const int b = blockIdx.x >> 2, sel = blockIdx.x & 3;
  for (int i = tid; i < TT; i += 256) s_a[i] = attn[b * TT + i];
  __syncthreads();

  if (tid < 64) {  // wave 0 only: wave-synchronous, no barriers
    if (blockIdx.x == 0) {  // zero accumulators (ws poisoned each call)
      acc[lane] = 0.0;
      if (lane < 2) acc[64 + lane] = 0.0;
    }
    float v[32];
    float med = 0.f, mx = 0.f;
    if (sel >= 2) {
      // median = mean of 1024th/1025th largest values (exact order stats)
#pragma unroll
      for (int r = 0; r < 32; r++) v[r] = s_a[r * 64 + lane];
      const float v1 = kth_val(v, 1024, 0x3F800000u);
      const float v2 = kth_val(v, 1025, __float_as_uint(v1));
      med = 0.5f * (v1 + v2);
    }
    if (sel == 1) {
      float m = 0.f;
#pragma unroll
      for (int r = 0; r < 32; r++) m = fmaxf(m, s_a[r * 64 + lane]);
      mx = wmax_bc(m);
    }
#pragma unroll
    for (int r = 0; r < 32; r++) {
      const int i = r * 64 + lane;
      const float a = s_a[i];
      float score;
      if (sel == 0) {
        score = a * drop[b * TT + i];
      } else if (sel == 1) {
        score = (mx - a) * drop[b * TT + i];
      } else {
        bool sall = true, ball = true, sany = false, bany = false;
#pragma unroll
        for (int o = -3; o <= 3; o++) {
          const int t = i + o;
          const bool one = (t >= 0 && t < TT) ? (s_a[t] > med) : false;  // 0-pad
          if (o >= -1 && o <= 1) { sall = sall && one; sany = sany || one; }
          ball = ball && one;
          bany = bany || one;
        }
        score = (sel == 2) ? ((sall && !ball) ? a : 0.f)    // er3 && !er7
                           : ((bany && !sany) ? a : 0.f);   // dl7 && !dl3
      }
      v[r] = score;
    }
    const unsigned K = (sel < 2) ? KEASY : KHARD;
    const unsigned hiS = (sel < 2) ? 0x40200000u : 0x3F800000u;  // 2.5 / 1.0
    const float ss = kth_val(v, K, hiS);
    // JAX stable top-k set: all (score > ss) plus the (K - c_gt) smallest-
    // index elements with score == ss.
    unsigned cgt = 0;
#pragma unroll
    for (int r = 0; r < 32; r++) cgt += (unsigned)__popcll(__ballot(v[r] > ss));
    unsigned need = K - cgt;
    unsigned base = 0;
    const u64 lmask = (1ull << lane) - 1;
    int* dst = idxb + sel * (BB * KEASY) + b * KEASY;
#pragma unroll
    for (int r = 0; r < 32; r++) {
      const bool gt = v[r] > ss;
      const bool eq = v[r] == ss;
      const u64 beq = __ballot(eq);
      const unsigned neq = (unsigned)__popcll(beq);
      const unsigned take = (need < neq) ? need : neq;
      const bool tk = eq && ((unsigned)__popcll(beq & lmask) < take);
      const u64 bsel = __ballot(gt || tk);
      if (gt || tk) {
        const unsigned pos = base + (unsigned)__popcll(bsel & lmask);
        dst[pos] = r * 64 + lane;
        s_idx[pos] = r * 64 + lane;
      }
      base += (unsigned)__popcll(bsel);
      need -= take;
    }
  }
  __syncthreads();

  // slog for this block's selected rows: sum_d log(var+eps), 4 waves
  const int Ksel = (sel < 2) ? KEASY : KHARD;
  for (int j = wid; j < Ksel; j += 4) {
    const int t = s_idx[j];
    const float* row = var + ((size_t)b * TT + t) * DD;
    float a2 = 0.f;
#pragma unroll
    for (int c = 0; c < 2; c++) {
      float4 vv = *(const float4*)(row + c * 256 + lane * 4);
      a2 += __logf(vv.x + EPSF) + __logf(vv.y + EPSF) +
            __logf(vv.z + EPSF) + __logf(vv.w + EPSF);
    }
    a2 = wsum63(a2);
    if (lane == 63) slogb[sel * 640 + b * 40 + j] = a2;
  }
}

// =======================================================================
// k2: blocks [0,64) = KL for (b=blk>>2, klid=blk&3); block 64 = distill
// partial reduce; block 65 = ortho. KL uses the 2-dot form:
//   dist(p,q) = 0.5*dot(mp^2+cvp, r) - dot(mp, mq*r)
//             + [0.5*dot(mq^2, r) + 0.5*slogq] - 0.5*slogp - 256
// with r = 1/(vq+eps). All 20 p-rows staged once in LDS (80 KB), 40 q-rows
// streamed with prefetch; ONE DPP reduce per (p,q) pair.
// klid0: p=hard_act(2) q=easy_act(0); klid1: p=hard_act q=easy_bkg(1)
// klid2: p=hard_bkg(3) q=easy_bkg;    klid3: p=hard_bkg q=easy_act
// =======================================================================
__global__ __launch_bounds__(256, 1) void k_part2(const float* __restrict__ mu,
                                                  const float* __restrict__ var,
                                                  const int* __restrict__ idxb,
                                                  const float* __restrict__ slogb,
                                                  const float* __restrict__ part,
                                                  const float* __restrict__ text,
                                                  double* __restrict__ acc) {
  __shared__ __align__(16) float smem[2 * KHARD * DD];  // 80 KB
  const int tid = threadIdx.x, wid = tid >> 6, lane = tid & 63;
  const int blk = blockIdx.x;

  if (blk < 64) {
    const int b = blk >> 2, klid = blk & 3;
    const int psel = (klid < 2) ? 2 : 3;
    const int qsel = (klid == 0 || klid == 3) ? 0 : 1;
    float* sP1 = smem;              // [20][512] mp^2 + cvp
    float* sP2 = smem + KHARD * DD; // [20][512] mp
    __shared__ float sSlogP[KHARD];
    __shared__ float s_out[4];
    if (tid < KHARD) sSlogP[tid] = slogb[psel * 640 + b * 40 + tid];
    for (int i = tid; i < KHARD * 128; i += 256) {
      const int p = i >> 7, c = (i & 127) * 4;
      const int t = idxb[psel * 640 + b * 40 + p];
      const size_t base = ((size_t)b * TT + t) * DD + c;
      const float4 m = *(const float4*)(mu + base);
      const float4 vv = *(const float4*)(var + base);
      float4 p1;
      p1.x = fmaf(m.x, m.x, vv.x + EPSF);
      p1.y = fmaf(m.y, m.y, vv.y + EPSF);
      p1.z = fmaf(m.z, m.z, vv.z + EPSF);
      p1.w = fmaf(m.w, m.w, vv.w + EPSF);
      *(float4*)(sP1 + p * DD + c) = p1;
      *(float4*)(sP2 + p * DD + c) = m;
    }
    __syncthreads();

    const int d0 = lane * 4, d1 = 256 + lane * 4;
    const int qbase_i = qsel * 640 + b * 40;
    float wacc = 0.f;
    // prefetch q0 for this wave
    int qidx = idxb[qbase_i + wid];
    float slq = slogb[qbase_i + wid];
    const float* qm = mu + ((size_t)b * TT + qidx) * DD;
    const float* qv = var + ((size_t)b * TT + qidx) * DD;
    float4 mqa = *(const float4*)(qm + d0);
    float4 mqb = *(const float4*)(qm + d1);
    float4 vqa = *(const float4*)(qv + d0);
    float4 vqb = *(const float4*)(qv + d1);
#pragma unroll 1
    for (int t = 0; t < 10; t++) {
      const float4 cma = mqa, cmb = mqb, cva = vqa, cvb = vqb;
      const float cslq = slq;
      if (t < 9) {
        const int iqn = wid + 4 * (t + 1);
        qidx = idxb[qbase_i + iqn];
        slq = slogb[qbase_i + iqn];
        const float* nm = mu + ((size_t)b * TT + qidx) * DD;
        const float* nv = var + ((size_t)b * TT + qidx) * DD;
        mqa = *(const float4*)(nm + d0);
        mqb = *(const float4*)(nm + d1);
        vqa = *(const float4*)(nv + d0);
        vqb = *(const float4*)(nv + d1);
      }
      float4 ra, rb, qra, qrb;
      ra.x = 1.0f / (cva.x + EPSF); ra.y = 1.0f / (cva.y + EPSF);
      ra.z = 1.0f / (cva.z + EPSF); ra.w = 1.0f / (cva.w + EPSF);
      rb.x = 1.0f / (cvb.x + EPSF); rb.y = 1.0f / (cvb.y + EPSF);
      rb.z = 1.0f / (cvb.z + EPSF); rb.w = 1.0f / (cvb.w + EPSF);
      qra.x = cma.x * ra.x; qra.y = cma.y * ra.y;
      qra.z = cma.z * ra.z; qra.w = cma.w * ra.w;
      qrb.x = cmb.x * rb.x; qrb.y = cmb.y * rb.y;
      qrb.z = cmb.z * rb.z; qrb.w = cmb.w * rb.w;
      float cqp = cma.x * qra.x + cma.y * qra.y + cma.z * qra.z + cma.w * qra.w +
                  cmb.x * qrb.x + cmb.y * qrb.y + cmb.z * qrb.z + cmb.w * qrb.w;
      const float cq = wsum63(cqp);  // valid in lane 63 only
      for (int p = 0; p < KHARD; p++) {
        const float4 p1a = *(const float4*)(sP1 + p * DD + d0);
        const float4 p1b = *(const float4*)(sP1 + p * DD + d1);
        const float4 p2a = *(const float4*)(sP2 + p * DD + d0);
        const float4 p2b = *(const float4*)(sP2 + p * DD + d1);
        const float s1 = p1a.x * ra.x + p1a.y * ra.y + p1a.z * ra.z + p1a.w * ra.w +
                         p1b.x * rb.x + p1b.y * rb.y + p1b.z * rb.z + p1b.w * rb.w;
        const float s2 = p2a.x * qra.x + p2a.y * qra.y + p2a.z * qra.z + p2a.w * qra.w +
                         p2b.x * qrb.x + p2b.y * qrb.y + p2b.z * qrb.z + p2b.w * qrb.w;
        const float h = wsum63(fmaf(0.5f, s1, -s2));
        if (lane == 63) {
          const float dist = h + 0.5f * cq + 0.5f * cslq - 0.5f * sSlogP[p] - 256.0f;
          wacc += 1.0f / (dist + 1.0f);
        }
      }
    }
    if (lane == 63) s_out[wid] = wacc;
    __syncthreads();
    if (tid == 0)
      acc[klid * 16 + b] = (double)s_out[0] + s_out[1] + s_out[2] + s_out[3];
    return;
  }

  if (blk == 64) {  // distill partial reduce -> acc[64]
    double* sd = (double*)smem;
    double s = 0.0;
    for (int i = tid; i < 2048; i += 256) s += (double)part[i];
    sd[tid] = s;
    __syncthreads();
    for (int st = 128; st; st >>= 1) {
      if (tid < st) sd[tid] += sd[tid + st];
      __syncthreads();
    }
    if (tid == 0) acc[64] = sd[0];
    return;
  }

  // blk == 65: ortho = ||normalize(text) @ normalize(text)^T - I||_F -> acc[65]
  {
    float* s_e = smem;  // CC*DD = 40 KB
    __shared__ float s_red4[4];
    for (int r = wid; r < CC; r += 4) {
      float4 v[2];
      float ss = 0.f;
#pragma unroll
      for (int c = 0; c < 2; c++) {
        v[c] = *(const float4*)(text + r * DD + c * 256 + lane * 4);
        ss += v[c].x * v[c].x + v[c].y * v[c].y + v[c].z * v[c].z + v[c].w * v[c].w;
      }
      ss = wsum_bc(ss);
      const float n = fmaxf(sqrtf(ss), 1e-12f);
#pragma unroll
      for (int c = 0; c < 2; c++) {
        float4 w = v[c];
        w.x /= n; w.y /= n; w.z /= n; w.w /= n;
        *(float4*)(s_e + r * DD + c * 256 + lane * 4) = w;
      }
    }
    __syncthreads();
    float wss = 0.f;
    for (int p = wid; p < CC * CC; p += 4) {
      const int i = p / CC, j = p % CC;
      float dot = 0.f;
#pragma unroll
      for (int c = 0; c < 2; c++) {
        const int d0 = c * 256 + lane * 4;
        const float4 x = *(const float4*)(s_e + i * DD + d0);
        const float4 y = *(const float4*)(s_e + j * DD + d0);
        dot += x.x * y.x + x.y * y.y + x.z * y.z + x.w * y.w;
      }
      dot = wsum63(dot);
      if (lane == 63) {
        const float s = dot - (i == j ? 1.0f : 0.0f);
        wss += s * s;
      }
    }
    if (lane == 63) s_red4[wid] = wss;
    __syncthreads();
    if (tid == 0)
      acc[65] = (double)(s_red4[0] + s_red4[1] + s_red4[2] + s_red4[3]);
  }
}

// =======================================================================
// k3: tiny epilogue (1 block, 64 threads)
// =======================================================================
__global__ __launch_bounds__(64) void k_final(const double* __restrict__ acc,
                                              float* __restrict__ out) {
  __shared__ double sla[16], slb[16];
  const int tid = threadIdx.x;
  if (tid < 16) {
    const double pa = acc[0 * 16 + tid] / 800.0;
    const double na = acc[1 * 16 + tid] / 800.0;
    const double pb = acc[2 * 16 + tid] / 800.0;
    const double nb = acc[3 * 16 + tid] / 800.0;
    sla[tid] = -(log(pa) + log(1.0 - na));
    slb[tid] = -(log(pb) + log(1.0 - nb));
  }
  __syncthreads();
  if (tid == 0) {
    double act = 0.0, bkg = 0.0;
    for (int b = 0; b < 16; b++) { act += sla[b]; bkg += slb[b]; }
    act /= 16.0;
    bkg /= 16.0;
    const double distill = -log(acc[64] / (double)(BB * TT));
    const double ortho = sqrt(acc[65]);
    const double total = distill + act + bkg + ortho;
    out[0] = (float)total;
    out[1] = (float)distill;
    out[2] = (float)act;
    out[3] = (float)bkg;
    out[4] = (float)ortho;
  }
}

extern "C" void kernel_launch(void* const* d_in, const int* in_sizes, int n_in,
                              void* d_out, int out_size, void* d_ws, size_t ws_size,
                              hipStream_t stream) {
  const float* attn = (const float*)d_in[0];
  const float* mu   = (const float*)d_in[1];
  const float* var  = (const float*)d_in[2];
  const float* muc  = (const float*)d_in[3];
  const float* text = (const float*)d_in[4];
  const float* drop = (const float*)d_in[5];
  float* out = (float*)d_out;

  // workspace layout (~30 KB)
  double* acc  = (double*)d_ws;           // 66 doubles: [0..63] kl, [64] distill, [65] ortho
  int* idxb    = (int*)(acc + 66);        // 4*16*40 ints
  float* slogb = (float*)(idxb + 2560);   // 4*16*40 f32
  float* part  = (float*)(slogb + 2560);  // 2048 f32 distill partials

  k_main1<<<2112, 256, 0, stream>>>(attn, drop, mu, muc, var, idxb, slogb, part, acc);
  k_part2<<<66, 256, 0, stream>>>(mu, var, idxb, slogb, part, text, acc);
  k_final<<<1, 64, 0, stream>>>(acc, out);
}